// Round 7
// baseline (137.858 us; speedup 1.0000x reference)
//
#include <hip/hip_runtime.h>
#include <hip/hip_bf16.h>

// MixedScoresSDPA: out = softmax(MLP2(relu(MLP1([QK^T*scale, dmat])))) @ V
// B=8 H=8 M=N=512 D=64 HID=16, fp32 in/out.
// r7: r6 structure (8-wave blocks, 16 waves/CU, P-in-regs, V^T chunk-4 XOR
//     image) with the softmax-sum bookkeeping fixed: lsum is a lane-local
//     partial (lsum*scO + psum*fac1), reduced over lane-groups in the
//     epilogue and combined across partner waves via LDS.

typedef __attribute__((ext_vector_type(4))) float f32x4;
typedef __attribute__((ext_vector_type(8))) __bf16 bf16x8;
typedef __attribute__((ext_vector_type(4))) __bf16 bf16x4;

static __device__ __forceinline__ float rlf(float x) {   // force SGPR residency
    return __uint_as_float(__builtin_amdgcn_readfirstlane(__float_as_uint(x)));
}
static __device__ __forceinline__ void cvt2(float x, __bf16& h, __bf16& l) {
    h = (__bf16)x;                    // RNE f32->bf16
    l = (__bf16)(x - (float)h);       // residual
}
// XOR-swizzled index for [64][64] bf16 K tiles: chunk-of-8 ^ (row&7) -> conflict-free b128.
static __device__ __forceinline__ int sw64(int row, int col) {
    return row * 64 + ((((col >> 3) ^ (row & 7)) << 3) | (col & 7));
}
// async global->LDS, 16B per lane (dest = wave-uniform base + lane*16; mapping lane-linear)
static __device__ __forceinline__ void dma16(const __bf16* g, __bf16* l) {
    __builtin_amdgcn_global_load_lds(
        (const __attribute__((address_space(1))) unsigned*)g,
        (__attribute__((address_space(3))) unsigned*)l, 16, 0, 0);
}

#define B_ 8
#define H_ 8
#define M_ 512
#define N_ 512
#define D_ 64
#define HID_ 16

// ---------------- prep: K -> (KH,KL) sw64 images; V -> (VTH,VTL) transposed images
// with chunk-of-4 XOR (d&15) placement: image(d, pos*4+jj) = V[(pos^(d&15))*4+jj][d].
// ws layout per (bh,nt) [512 tiles]: 16384 bf16 = {KH,KL,VTH,VTL} x 4096 elems.
__global__ __launch_bounds__(256) void prep_kernel(
    const float* __restrict__ kg, const float* __restrict__ vg,
    __bf16* __restrict__ ws)
{
    __shared__ float vld[64 * 68];   // V tile f32, padded stride 68
    const int t   = threadIdx.x;
    const int blk = blockIdx.x;                   // bh*8 + nt
    const long base = (long)blk * 4096;           // element offset of this 64x64 tile
    __bf16* out = ws + (long)blk * 16384;

    // stage V tile into LDS (row-major, padded)
#pragma unroll
    for (int it = 0; it < 4; ++it) {
        const int e = it * 1024 + t * 4;
        const int rr = e >> 6, c0 = e & 63;
        f32x4 v4 = *(const f32x4*)(vg + base + e);
        *(f32x4*)(vld + rr * 68 + c0) = v4;
    }

    // K images (straight from global; row-major with chunk-of-8 pre-swizzle)
#pragma unroll
    for (int qq = t; qq < 512; qq += 256) {
        const int row = qq >> 3, c = qq & 7;
        const float* src = kg + base + row * 64 + ((c ^ (row & 7)) << 3);
        f32x4 a = *(const f32x4*)src;
        f32x4 b4 = *(const f32x4*)(src + 4);
        bf16x8 hv, lv;
#pragma unroll
        for (int j = 0; j < 4; ++j) {
            __bf16 h, l;
            cvt2(a[j], h, l);  hv[j] = h;     lv[j] = l;
            cvt2(b4[j], h, l); hv[4 + j] = h; lv[4 + j] = l;
        }
        *(bf16x8*)(out + qq * 8) = hv;            // KH
        *(bf16x8*)(out + 4096 + qq * 8) = lv;     // KL
    }
    __syncthreads();

    // V^T images: memory pos holds logical chunk pos^(d&15); 2 chunks per iter
#pragma unroll
    for (int qq = t; qq < 512; qq += 256) {
        const int d = qq & 63, c = qq >> 6;       // c in 0..7 -> positions 2c, 2c+1
        bf16x8 hv, lv;
#pragma unroll
        for (int dd = 0; dd < 2; ++dd) {
            const int nb = (((2 * c + dd) ^ (d & 15)) << 2);
#pragma unroll
            for (int jj = 0; jj < 4; ++jj) {
                __bf16 h, l;
                cvt2(vld[(nb + jj) * 68 + d], h, l);
                hv[dd * 4 + jj] = h; lv[dd * 4 + jj] = l;
            }
        }
        const int pos = d * 64 + c * 8;
        *(bf16x8*)(out + 8192 + pos) = hv;        // VTH
        *(bf16x8*)(out + 12288 + pos) = lv;       // VTL
    }
}

// ---------------- main kernel: 512 threads = 8 waves; wave w: rows (w&3)*16, n-half w>>2
__global__ __launch_bounds__(512, 4) void msdpa_kernel(
    const float* __restrict__ qg, const __bf16* __restrict__ ws,
    const float* __restrict__ dg, const float* __restrict__ w1g,
    const float* __restrict__ b1g, const float* __restrict__ w2g,
    float* __restrict__ outg)
{
    extern __shared__ __bf16 smem[];
    // buf0 @0 (16384 elems), buf1 @16384; each: KH 0, KL 4096, VTH 8192, VTL 12288.
    // xchg @32768 (float): xm[8][16] (per-tile max), xls[4][16] (epilogue sums).
    float* xm  = (float*)(smem + 32768);
    float* xls = xm + 128;

    const int tid  = threadIdx.x;
    const int lane = tid & 63;
    const int wv   = tid >> 6;
    const int r16  = lane & 15;
    const int g    = lane >> 4;
    const int rw   = wv & 3;    // row-group (16 rows)
    const int hn   = wv >> 2;   // n-half of each 64-tile

    const int bm = blockIdx.x;
    const int h  = blockIdx.y;
    const int b  = blockIdx.z;

    const long bh = (long)(b * H_ + h);
    const __bf16* wsbh = ws + bh * (8L * 16384);

    __bf16* bcur = smem;
    __bf16* bnxt = smem + 16384;

    // ---- issue tile-0 DMA first; overlap with constant/Q setup below
#pragma unroll
    for (int i = 0; i < 4; ++i)
        dma16(wsbh + i * 4096 + tid * 8, bcur + i * 4096 + tid * 8);

    // per-head MLP constants -> SGPRs. scale 1/8 in af, log2e*0.5 in wa; b2 dropped.
    // relu(u)=(u+|u|)/2 -> score*log2e = A*s + C*d + B0 + sum_f wa_f*|af_f*s+cf_f*d+bf_f|
    const float* w1h = w1g + h * 2 * HID_;
    const float* b1h = b1g + h * HID_;
    const float* w2h = w2g + h * HID_;
    float af[HID_], cf[HID_], bf_[HID_], wa[HID_];
    float A = 0.f, C = 0.f, B0 = 0.f;
#pragma unroll
    for (int f = 0; f < HID_; ++f) {
        af[f] = rlf(w1h[f]) * 0.125f;
        cf[f] = rlf(w1h[HID_ + f]);
        bf_[f] = rlf(b1h[f]);
        wa[f] = rlf(w2h[f]) * (1.4426950408889634f * 0.5f);
        A  = fmaf(wa[f], af[f], A);
        C  = fmaf(wa[f], cf[f], C);
        B0 = fmaf(wa[f], bf_[f], B0);
    }

    // Q fragments (hi/lo bf16), B-operand: lane holds Q[m=rw*16+r16][d=ks*32+g*8+j]
    const float* qbase = qg + (bh * M_ + (long)bm * 64 + rw * 16 + r16) * D_;
    bf16x8 qh[2], ql[2];
#pragma unroll
    for (int ks = 0; ks < 2; ++ks) {
        f32x4 x0 = *(const f32x4*)(qbase + ks * 32 + g * 8);
        f32x4 x1 = *(const f32x4*)(qbase + ks * 32 + g * 8 + 4);
        bf16x8 hv, lv;
#pragma unroll
        for (int j = 0; j < 4; ++j) {
            __bf16 h_, l_;
            cvt2(x0[j], h_, l_); hv[j] = h_; lv[j] = l_;
            cvt2(x1[j], h_, l_); hv[4 + j] = h_; lv[4 + j] = l_;
        }
        qh[ks] = hv; ql[ks] = lv;
    }

    // dmat prefetch (this wave's 32-n half only)
    const float* dmp = dg + ((long)b * M_ + (long)bm * 64 + rw * 16 + r16) * N_
                          + hn * 32 + g * 4;
    f32x4 dmvc[2], dmvn[2];
#pragma unroll
    for (int n16 = 0; n16 < 2; ++n16)
        dmvc[n16] = *(const f32x4*)(dmp + n16 * 16);

    f32x4 oacc[4];
#pragma unroll
    for (int dt = 0; dt < 4; ++dt) oacc[dt] = f32x4{0.f, 0.f, 0.f, 0.f};
    float mrun = -1e30f, lsum = 0.0f;

    __syncthreads();   // vmcnt(0): tile-0 staged (setup above overlapped the DMA)

    for (int nt = 0; nt < 8; ++nt) {
        // ---- issue next tile's DMA + dmat prefetch (in flight through compute)
        if (nt < 7) {
            const __bf16* tile = wsbh + (nt + 1) * 16384;
#pragma unroll
            for (int i = 0; i < 4; ++i)
                dma16(tile + i * 4096 + tid * 8, bnxt + i * 4096 + tid * 8);
#pragma unroll
            for (int n16 = 0; n16 < 2; ++n16)
                dmvn[n16] = *(const f32x4*)(dmp + (nt + 1) * 64 + n16 * 16);
        }

        __bf16* KH  = bcur;
        __bf16* KL  = bcur + 4096;
        __bf16* VTH = bcur + 8192;
        __bf16* VTL = bcur + 12288;

        // ---- QK^T over this wave's 32-n half (swapped: A=K, B=Q) -> S^T
        f32x4 sacc[2];
#pragma unroll
        for (int n16 = 0; n16 < 2; ++n16) sacc[n16] = f32x4{0.f, 0.f, 0.f, 0.f};
#pragma unroll
        for (int n16 = 0; n16 < 2; ++n16) {
            const int row = hn * 32 + n16 * 16 + r16;
#pragma unroll
            for (int ks = 0; ks < 2; ++ks) {
                const int off = sw64(row, ks * 32 + g * 8);
                bf16x8 kh_ = *(const bf16x8*)(KH + off);
                bf16x8 kl_ = *(const bf16x8*)(KL + off);
                sacc[n16] = __builtin_amdgcn_mfma_f32_16x16x32_bf16(kh_, qh[ks], sacc[n16], 0, 0, 0);
                sacc[n16] = __builtin_amdgcn_mfma_f32_16x16x32_bf16(kh_, ql[ks], sacc[n16], 0, 0, 0);
                sacc[n16] = __builtin_amdgcn_mfma_f32_16x16x32_bf16(kl_, qh[ks], sacc[n16], 0, 0, 0);
            }
        }
        // lane holds S^T: m_loc = r16, n = hn*32 + n16*16 + 4g + r

        // ---- MLP via relu->abs (8 elems/thread)
        float ms[2][4];
#pragma unroll
        for (int n16 = 0; n16 < 2; ++n16)
#pragma unroll
            for (int r = 0; r < 4; ++r) {
                const float s = sacc[n16][r], d = dmvc[n16][r];
                float acc = fmaf(A, s, fmaf(C, d, B0));
#pragma unroll
                for (int f = 0; f < HID_; ++f) {
                    const float u = fmaf(af[f], s, fmaf(cf[f], d, bf_[f]));
                    acc = fmaf(wa[f], fabsf(u), acc);
                }
                ms[n16][r] = acc;
            }

        // ---- local softmax over the 32-n half (row m=r16; reduce across g)
        float mloc = fmaxf(fmaxf(fmaxf(ms[0][0], ms[0][1]), fmaxf(ms[0][2], ms[0][3])),
                           fmaxf(fmaxf(ms[1][0], ms[1][1]), fmaxf(ms[1][2], ms[1][3])));
        mloc = fmaxf(mloc, __shfl_xor(mloc, 16));
        mloc = fmaxf(mloc, __shfl_xor(mloc, 32));
        float p[8], psum = 0.f;
#pragma unroll
        for (int n16 = 0; n16 < 2; ++n16)
#pragma unroll
            for (int r = 0; r < 4; ++r) {
                const float pv = exp2f(ms[n16][r] - mloc);
                p[n16 * 4 + r] = pv;
                psum += pv;
            }
        if (g == 0) xm[wv * 16 + r16] = mloc;   // export half-row max only
        __syncthreads();   // BAR1: exchange visible

        // ---- cross-wave max combine with partner (wv^4: other n-half, same rows)
        const float mloc2 = xm[(wv ^ 4) * 16 + r16];
        const float mnew = fmaxf(mrun, fmaxf(mloc, mloc2));
        const float scO  = exp2f(mrun - mnew);
        const float fac1 = exp2f(mloc - mnew);
        mrun = mnew;
        // lane-local partial sum (this lane's 8 p's); g/partner reduction deferred
        lsum = fmaf(lsum, scO, psum * fac1);

        // ---- P fragment in registers (zero-shuffle): j-th k-slot is n =
        //      hn*32 + 16*(j>>2) + 4g + (j&3) == lane's own p[(j>>2)*4 + (j&3)]
        bf16x8 pa, pb;
#pragma unroll
        for (int j = 0; j < 8; ++j) {
            __bf16 h_, l_;
            cvt2(p[j] * fac1, h_, l_);
            pa[j] = h_; pb[j] = l_;
        }

        // ---- rescale O (rows m_loc = 4g+r; scale at lane m_loc)
        float scm[4];
#pragma unroll
        for (int r = 0; r < 4; ++r) scm[r] = __shfl(scO, g * 4 + r);
#pragma unroll
        for (int dt = 0; dt < 4; ++dt)
#pragma unroll
            for (int r = 0; r < 4; ++r) oacc[dt][r] *= scm[r];

        // ---- PV over this wave's 32-n half: V b64-pair reads (pos = chunk^(d&15))
#pragma unroll
        for (int dt = 0; dt < 4; ++dt) {
            const int rowb = (dt * 16 + r16) * 64;          // d&15 == r16
            const int p0 = ((hn * 8 + g) ^ r16) * 4;
            const int p1 = ((hn * 8 + 4 + g) ^ r16) * 4;
            bf16x4 vh0 = *(const bf16x4*)(VTH + rowb + p0);
            bf16x4 vh1 = *(const bf16x4*)(VTH + rowb + p1);
            bf16x4 vl0 = *(const bf16x4*)(VTL + rowb + p0);
            bf16x4 vl1 = *(const bf16x4*)(VTL + rowb + p1);
            bf16x8 vh = __builtin_shufflevector(vh0, vh1, 0, 1, 2, 3, 4, 5, 6, 7);
            bf16x8 vl = __builtin_shufflevector(vl0, vl1, 0, 1, 2, 3, 4, 5, 6, 7);
            oacc[dt] = __builtin_amdgcn_mfma_f32_16x16x32_bf16(pa, vh, oacc[dt], 0, 0, 0);
            oacc[dt] = __builtin_amdgcn_mfma_f32_16x16x32_bf16(pa, vl, oacc[dt], 0, 0, 0);
            oacc[dt] = __builtin_amdgcn_mfma_f32_16x16x32_bf16(pb, vh, oacc[dt], 0, 0, 0);
        }

        // ---- close tile: drain next DMA, swap buffers
        __syncthreads();   // BAR2: vmcnt(0)+lgkmcnt(0)+barrier
        __bf16* tmp = bcur; bcur = bnxt; bnxt = tmp;
#pragma unroll
        for (int n16 = 0; n16 < 2; ++n16) dmvc[n16] = dmvn[n16];
    }

    // ---- epilogue: finish row sums (reduce over g), combine across wave pairs
    lsum += __shfl_xor(lsum, 16);
    lsum += __shfl_xor(lsum, 32);
    // lanes with r16==m now hold this wave's half-row sum for row m (scale mrun;
    // identical mrun across partners by symmetric max exchange)

    float* obuf = (float*)smem;   // KV buffers dead after last BAR2
    if (hn == 1) {
        if (g == 0) xls[rw * 16 + r16] = lsum;
#pragma unroll
        for (int dt = 0; dt < 4; ++dt)
#pragma unroll
            for (int r = 0; r < 4; ++r)
                obuf[rw * 1024 + (g * 4 + r) * 64 + dt * 16 + r16] = oacc[dt][r];
    }
    __syncthreads();
    if (hn == 0) {
        const float Ltot = lsum + xls[rw * 16 + r16];   // both halves, same scale
        float linv[4];
#pragma unroll
        for (int r = 0; r < 4; ++r) linv[r] = 1.0f / __shfl(Ltot, g * 4 + r);
        float* obase = outg + (bh * M_ + (long)bm * 64 + rw * 16) * D_;
#pragma unroll
        for (int dt = 0; dt < 4; ++dt)
#pragma unroll
            for (int r = 0; r < 4; ++r) {
                const float o2 = obuf[rw * 1024 + (g * 4 + r) * 64 + dt * 16 + r16];
                obase[(g * 4 + r) * D_ + dt * 16 + r16] = (oacc[dt][r] + o2) * linv[r];
            }
    }
}

extern "C" void kernel_launch(void* const* d_in, const int* in_sizes, int n_in,
                              void* d_out, int out_size, void* d_ws, size_t ws_size,
                              hipStream_t stream) {
    const float* q  = (const float*)d_in[0];
    const float* k  = (const float*)d_in[1];
    const float* v  = (const float*)d_in[2];
    const float* dm = (const float*)d_in[3];
    const float* w1 = (const float*)d_in[4];
    const float* b1 = (const float*)d_in[5];
    const float* w2 = (const float*)d_in[6];
    // d_in[7] = mix_b2: unused (softmax shift-invariant)
    float* out = (float*)d_out;
    __bf16* ws = (__bf16*)d_ws;   // needs 512*16384*2B = 16.8 MB

    prep_kernel<<<dim3(512), dim3(256), 0, stream>>>(k, v, ws);

    (void)hipFuncSetAttribute(reinterpret_cast<const void*>(msdpa_kernel),
                              hipFuncAttributeMaxDynamicSharedMemorySize, 66560);
    dim3 grid(M_ / 64, H_, B_);   // 512 blocks x 8 waves = 16 waves/CU
    msdpa_kernel<<<grid, dim3(512), 66560, stream>>>(q, ws, dm, w1, b1, w2, out);
}

// Round 8
// 134.213 us; speedup vs baseline: 1.0272x; 1.0272x over previous
//
#include <hip/hip_runtime.h>
#include <hip/hip_bf16.h>

// MixedScoresSDPA: out = softmax(MLP2(relu(MLP1([QK^T*scale, dmat])))) @ V
// B=8 H=8 M=N=512 D=64 HID=16, fp32 in/out.
// r8: r7 structure minus the mid-loop barrier (independent partner softmax
//     states, merged in epilogue) + packed-f16 MLP (pk_fma_f16 + fdot2,
//     f32 accumulate). 1 barrier/tile.

typedef __attribute__((ext_vector_type(4))) float f32x4;
typedef __attribute__((ext_vector_type(8))) __bf16 bf16x8;
typedef __attribute__((ext_vector_type(4))) __bf16 bf16x4;
typedef __attribute__((ext_vector_type(2))) _Float16 h16x2;

union HU { h16x2 h; unsigned u; };

static __device__ __forceinline__ float rlf(float x) {   // force SGPR residency
    return __uint_as_float(__builtin_amdgcn_readfirstlane(__float_as_uint(x)));
}
static __device__ __forceinline__ void cvt2(float x, __bf16& h, __bf16& l) {
    h = (__bf16)x;                    // RNE f32->bf16
    l = (__bf16)(x - (float)h);       // residual
}
// XOR-swizzled index for [64][64] bf16 K tiles: chunk-of-8 ^ (row&7) -> conflict-free b128.
static __device__ __forceinline__ int sw64(int row, int col) {
    return row * 64 + ((((col >> 3) ^ (row & 7)) << 3) | (col & 7));
}
// async global->LDS, 16B per lane (dest = wave-uniform base + lane*16; mapping lane-linear)
static __device__ __forceinline__ void dma16(const __bf16* g, __bf16* l) {
    __builtin_amdgcn_global_load_lds(
        (const __attribute__((address_space(1))) unsigned*)g,
        (__attribute__((address_space(3))) unsigned*)l, 16, 0, 0);
}

#define B_ 8
#define H_ 8
#define M_ 512
#define N_ 512
#define D_ 64
#define HID_ 16

// ---------------- prep: K -> (KH,KL) sw64 images; V -> (VTH,VTL) transposed images
// with chunk-of-4 XOR (d&15) placement: image(d, pos*4+jj) = V[(pos^(d&15))*4+jj][d].
// ws layout per (bh,nt) [512 tiles]: 16384 bf16 = {KH,KL,VTH,VTL} x 4096 elems.
__global__ __launch_bounds__(256) void prep_kernel(
    const float* __restrict__ kg, const float* __restrict__ vg,
    __bf16* __restrict__ ws)
{
    __shared__ float vld[64 * 68];   // V tile f32, padded stride 68
    const int t   = threadIdx.x;
    const int blk = blockIdx.x;                   // bh*8 + nt
    const long base = (long)blk * 4096;           // element offset of this 64x64 tile
    __bf16* out = ws + (long)blk * 16384;

    // stage V tile into LDS (row-major, padded)
#pragma unroll
    for (int it = 0; it < 4; ++it) {
        const int e = it * 1024 + t * 4;
        const int rr = e >> 6, c0 = e & 63;
        f32x4 v4 = *(const f32x4*)(vg + base + e);
        *(f32x4*)(vld + rr * 68 + c0) = v4;
    }

    // K images (straight from global; row-major with chunk-of-8 pre-swizzle)
#pragma unroll
    for (int qq = t; qq < 512; qq += 256) {
        const int row = qq >> 3, c = qq & 7;
        const float* src = kg + base + row * 64 + ((c ^ (row & 7)) << 3);
        f32x4 a = *(const f32x4*)src;
        f32x4 b4 = *(const f32x4*)(src + 4);
        bf16x8 hv, lv;
#pragma unroll
        for (int j = 0; j < 4; ++j) {
            __bf16 h, l;
            cvt2(a[j], h, l);  hv[j] = h;     lv[j] = l;
            cvt2(b4[j], h, l); hv[4 + j] = h; lv[4 + j] = l;
        }
        *(bf16x8*)(out + qq * 8) = hv;            // KH
        *(bf16x8*)(out + 4096 + qq * 8) = lv;     // KL
    }
    __syncthreads();

    // V^T images: memory pos holds logical chunk pos^(d&15); 2 chunks per iter
#pragma unroll
    for (int qq = t; qq < 512; qq += 256) {
        const int d = qq & 63, c = qq >> 6;       // c in 0..7 -> positions 2c, 2c+1
        bf16x8 hv, lv;
#pragma unroll
        for (int dd = 0; dd < 2; ++dd) {
            const int nb = (((2 * c + dd) ^ (d & 15)) << 2);
#pragma unroll
            for (int jj = 0; jj < 4; ++jj) {
                __bf16 h, l;
                cvt2(vld[(nb + jj) * 68 + d], h, l);
                hv[dd * 4 + jj] = h; lv[dd * 4 + jj] = l;
            }
        }
        const int pos = d * 64 + c * 8;
        *(bf16x8*)(out + 8192 + pos) = hv;        // VTH
        *(bf16x8*)(out + 12288 + pos) = lv;       // VTL
    }
}

// ---------------- main kernel: 512 threads = 8 waves; wave w: rows (w&3)*16, n-half w>>2
__global__ __launch_bounds__(512, 4) void msdpa_kernel(
    const float* __restrict__ qg, const __bf16* __restrict__ ws,
    const float* __restrict__ dg, const float* __restrict__ w1g,
    const float* __restrict__ b1g, const float* __restrict__ w2g,
    float* __restrict__ outg)
{
    extern __shared__ __bf16 smem[];
    // buf0 @0 (16384 elems), buf1 @16384; each: KH 0, KL 4096, VTH 8192, VTL 12288.
    // xchg @32768 (float[128]): [0:64) partner mrun, [64:128) partner lsum (epilogue only).
    float* xm = (float*)(smem + 32768);

    const int tid  = threadIdx.x;
    const int lane = tid & 63;
    const int wv   = tid >> 6;
    const int r16  = lane & 15;
    const int g    = lane >> 4;
    const int rw   = wv & 3;    // row-group (16 rows)
    const int hn   = wv >> 2;   // n-half of each 64-tile

    const int bm = blockIdx.x;
    const int h  = blockIdx.y;
    const int b  = blockIdx.z;

    const long bh = (long)(b * H_ + h);
    const __bf16* wsbh = ws + bh * (8L * 16384);

    __bf16* bcur = smem;
    __bf16* bnxt = smem + 16384;

    // ---- issue tile-0 DMA first; overlap with constant/Q setup below
#pragma unroll
    for (int i = 0; i < 4; ++i)
        dma16(wsbh + i * 4096 + tid * 8, bcur + i * 4096 + tid * 8);

    // per-head MLP constants. scale 1/8 in af, log2e*0.5 in wa; b2 dropped.
    // relu(u)=(u+|u|)/2 -> score*log2e = A*s + C*d + B0 + sum_f wa_f*|af_f*s+cf_f*d+bf_f|
    const float* w1h = w1g + h * 2 * HID_;
    const float* b1h = b1g + h * HID_;
    const float* w2h = w2g + h * HID_;
    float af[HID_], cf[HID_], bf_[HID_], wa[HID_];
    float A = 0.f, C = 0.f, B0 = 0.f;
#pragma unroll
    for (int f = 0; f < HID_; ++f) {
        af[f] = rlf(w1h[f]) * 0.125f;
        cf[f] = rlf(w1h[HID_ + f]);
        bf_[f] = rlf(b1h[f]);
        wa[f] = rlf(w2h[f]) * (1.4426950408889634f * 0.5f);
        A  = fmaf(wa[f], af[f], A);
        C  = fmaf(wa[f], cf[f], C);
        B0 = fmaf(wa[f], bf_[f], B0);
    }
    // packed half2 constants for the f16 MLP (f-pairs)
    h16x2 af2[8], cf2[8], bf2[8], wa2[8];
#pragma unroll
    for (int fp = 0; fp < 8; ++fp) {
        af2[fp] = h16x2{(_Float16)af[2 * fp], (_Float16)af[2 * fp + 1]};
        cf2[fp] = h16x2{(_Float16)cf[2 * fp], (_Float16)cf[2 * fp + 1]};
        bf2[fp] = h16x2{(_Float16)bf_[2 * fp], (_Float16)bf_[2 * fp + 1]};
        wa2[fp] = h16x2{(_Float16)wa[2 * fp], (_Float16)wa[2 * fp + 1]};
    }

    // Q fragments (hi/lo bf16), B-operand: lane holds Q[m=rw*16+r16][d=ks*32+g*8+j]
    const float* qbase = qg + (bh * M_ + (long)bm * 64 + rw * 16 + r16) * D_;
    bf16x8 qh[2], ql[2];
#pragma unroll
    for (int ks = 0; ks < 2; ++ks) {
        f32x4 x0 = *(const f32x4*)(qbase + ks * 32 + g * 8);
        f32x4 x1 = *(const f32x4*)(qbase + ks * 32 + g * 8 + 4);
        bf16x8 hv, lv;
#pragma unroll
        for (int j = 0; j < 4; ++j) {
            __bf16 h_, l_;
            cvt2(x0[j], h_, l_); hv[j] = h_; lv[j] = l_;
            cvt2(x1[j], h_, l_); hv[4 + j] = h_; lv[4 + j] = l_;
        }
        qh[ks] = hv; ql[ks] = lv;
    }

    // dmat prefetch (this wave's 32-n half only)
    const float* dmp = dg + ((long)b * M_ + (long)bm * 64 + rw * 16 + r16) * N_
                          + hn * 32 + g * 4;
    f32x4 dmvc[2], dmvn[2];
#pragma unroll
    for (int n16 = 0; n16 < 2; ++n16)
        dmvc[n16] = *(const f32x4*)(dmp + n16 * 16);

    f32x4 oacc[4];
#pragma unroll
    for (int dt = 0; dt < 4; ++dt) oacc[dt] = f32x4{0.f, 0.f, 0.f, 0.f};
    float mrun = -1e30f, lsum = 0.0f;

    __syncthreads();   // vmcnt(0): tile-0 staged (setup above overlapped the DMA)

    for (int nt = 0; nt < 8; ++nt) {
        // ---- issue next tile's DMA + dmat prefetch (in flight through compute;
        //      drained only at the single closing barrier)
        if (nt < 7) {
            const __bf16* tile = wsbh + (nt + 1) * 16384;
#pragma unroll
            for (int i = 0; i < 4; ++i)
                dma16(tile + i * 4096 + tid * 8, bnxt + i * 4096 + tid * 8);
#pragma unroll
            for (int n16 = 0; n16 < 2; ++n16)
                dmvn[n16] = *(const f32x4*)(dmp + (nt + 1) * 64 + n16 * 16);
        }

        __bf16* KH  = bcur;
        __bf16* KL  = bcur + 4096;
        __bf16* VTH = bcur + 8192;
        __bf16* VTL = bcur + 12288;

        // ---- QK^T over this wave's 32-n half (swapped: A=K, B=Q) -> S^T
        f32x4 sacc[2];
#pragma unroll
        for (int n16 = 0; n16 < 2; ++n16) sacc[n16] = f32x4{0.f, 0.f, 0.f, 0.f};
#pragma unroll
        for (int n16 = 0; n16 < 2; ++n16) {
            const int row = hn * 32 + n16 * 16 + r16;
#pragma unroll
            for (int ks = 0; ks < 2; ++ks) {
                const int off = sw64(row, ks * 32 + g * 8);
                bf16x8 kh_ = *(const bf16x8*)(KH + off);
                bf16x8 kl_ = *(const bf16x8*)(KL + off);
                sacc[n16] = __builtin_amdgcn_mfma_f32_16x16x32_bf16(kh_, qh[ks], sacc[n16], 0, 0, 0);
                sacc[n16] = __builtin_amdgcn_mfma_f32_16x16x32_bf16(kh_, ql[ks], sacc[n16], 0, 0, 0);
                sacc[n16] = __builtin_amdgcn_mfma_f32_16x16x32_bf16(kl_, qh[ks], sacc[n16], 0, 0, 0);
            }
        }
        // lane holds S^T: m_loc = r16, n = hn*32 + n16*16 + 4g + r

        // ---- MLP: packed-f16 hinges, f32 accumulate via v_dot2_f32_f16
        float ms[2][4];
#pragma unroll
        for (int n16 = 0; n16 < 2; ++n16)
#pragma unroll
            for (int r = 0; r < 4; ++r) {
                const float s = sacc[n16][r], d = dmvc[n16][r];
                const _Float16 sh = (_Float16)s, dh = (_Float16)d;
                const h16x2 s2 = h16x2{sh, sh}, d2 = h16x2{dh, dh};
                float acc = fmaf(A, s, fmaf(C, d, B0));
#pragma unroll
                for (int fp = 0; fp < 8; ++fp) {
                    h16x2 u2 = __builtin_elementwise_fma(
                        af2[fp], s2, __builtin_elementwise_fma(cf2[fp], d2, bf2[fp]));
                    HU hu; hu.h = u2; hu.u &= 0x7FFF7FFFu;   // packed |u|
                    acc = __builtin_amdgcn_fdot2(wa2[fp], hu.h, acc, false);
                }
                ms[n16][r] = acc;
            }

        // ---- independent online softmax over this wave's 32-n half
        float mloc = fmaxf(fmaxf(fmaxf(ms[0][0], ms[0][1]), fmaxf(ms[0][2], ms[0][3])),
                           fmaxf(fmaxf(ms[1][0], ms[1][1]), fmaxf(ms[1][2], ms[1][3])));
        mloc = fmaxf(mloc, __shfl_xor(mloc, 16));
        mloc = fmaxf(mloc, __shfl_xor(mloc, 32));
        const float mnew = fmaxf(mrun, mloc);
        const float scO  = exp2f(mrun - mnew);
        const float fac1 = exp2f(mloc - mnew);
        mrun = mnew;

        float p[8], psum = 0.f;
#pragma unroll
        for (int n16 = 0; n16 < 2; ++n16)
#pragma unroll
            for (int r = 0; r < 4; ++r) {
                const float pv = exp2f(ms[n16][r] - mloc);
                p[n16 * 4 + r] = pv;
                psum += pv;
            }
        lsum = fmaf(lsum, scO, psum * fac1);   // lane-local partial

        // ---- P fragment in registers (zero-shuffle): j-th k-slot is n =
        //      hn*32 + 16*(j>>2) + 4g + (j&3) == lane's own p[(j>>2)*4 + (j&3)]
        bf16x8 pa, pb;
#pragma unroll
        for (int j = 0; j < 8; ++j) {
            __bf16 h_, l_;
            cvt2(p[j] * fac1, h_, l_);
            pa[j] = h_; pb[j] = l_;
        }

        // ---- rescale O (rows m_loc = 4g+r; scale at lane m_loc)
        float scm[4];
#pragma unroll
        for (int r = 0; r < 4; ++r) scm[r] = __shfl(scO, g * 4 + r);
#pragma unroll
        for (int dt = 0; dt < 4; ++dt)
#pragma unroll
            for (int r = 0; r < 4; ++r) oacc[dt][r] *= scm[r];

        // ---- PV over this wave's 32-n half: V b64-pair reads (pos = chunk^(d&15))
#pragma unroll
        for (int dt = 0; dt < 4; ++dt) {
            const int rowb = (dt * 16 + r16) * 64;          // d&15 == r16
            const int p0 = ((hn * 8 + g) ^ r16) * 4;
            const int p1 = ((hn * 8 + 4 + g) ^ r16) * 4;
            bf16x4 vh0 = *(const bf16x4*)(VTH + rowb + p0);
            bf16x4 vh1 = *(const bf16x4*)(VTH + rowb + p1);
            bf16x4 vl0 = *(const bf16x4*)(VTL + rowb + p0);
            bf16x4 vl1 = *(const bf16x4*)(VTL + rowb + p1);
            bf16x8 vh = __builtin_shufflevector(vh0, vh1, 0, 1, 2, 3, 4, 5, 6, 7);
            bf16x8 vl = __builtin_shufflevector(vl0, vl1, 0, 1, 2, 3, 4, 5, 6, 7);
            oacc[dt] = __builtin_amdgcn_mfma_f32_16x16x32_bf16(pa, vh, oacc[dt], 0, 0, 0);
            oacc[dt] = __builtin_amdgcn_mfma_f32_16x16x32_bf16(pa, vl, oacc[dt], 0, 0, 0);
            oacc[dt] = __builtin_amdgcn_mfma_f32_16x16x32_bf16(pb, vh, oacc[dt], 0, 0, 0);
        }

        // ---- close tile: drain next DMA, swap buffers (single barrier per tile)
        __syncthreads();   // vmcnt(0)+lgkmcnt(0)+barrier
        __bf16* tmp = bcur; bcur = bnxt; bnxt = tmp;
#pragma unroll
        for (int n16 = 0; n16 < 2; ++n16) dmvc[n16] = dmvn[n16];
    }

    // ---- epilogue: finish row sums (reduce over g), merge partner states
    lsum += __shfl_xor(lsum, 16);
    lsum += __shfl_xor(lsum, 32);
    // every lane now holds (mrun, lsum) for its row r16 of this wave's n-half

    float* obuf = (float*)smem;   // KV buffers dead after last barrier
    if (hn == 1) {
        if (g == 0) { xm[rw * 16 + r16] = mrun; xm[64 + rw * 16 + r16] = lsum; }
#pragma unroll
        for (int dt = 0; dt < 4; ++dt)
#pragma unroll
            for (int r = 0; r < 4; ++r)
                obuf[rw * 1024 + (g * 4 + r) * 64 + dt * 16 + r16] = oacc[dt][r];
    }
    __syncthreads();
    if (hn == 0) {
        const float m2 = xm[rw * 16 + r16];
        const float l2 = xm[64 + rw * 16 + r16];
        const float mstar = fmaxf(mrun, m2);
        const float a1 = exp2f(mrun - mstar);
        const float a2 = exp2f(m2 - mstar);
        const float linv = 1.0f / fmaf(lsum, a1, l2 * a2);
        const float w1r_ = a1 * linv, w2r_ = a2 * linv;
        float w1r[4], w2r[4];
#pragma unroll
        for (int r = 0; r < 4; ++r) {
            w1r[r] = __shfl(w1r_, g * 4 + r);
            w2r[r] = __shfl(w2r_, g * 4 + r);
        }
        float* obase = outg + (bh * M_ + (long)bm * 64 + rw * 16) * D_;
#pragma unroll
        for (int dt = 0; dt < 4; ++dt)
#pragma unroll
            for (int r = 0; r < 4; ++r) {
                const float o2 = obuf[rw * 1024 + (g * 4 + r) * 64 + dt * 16 + r16];
                obase[(g * 4 + r) * D_ + dt * 16 + r16] =
                    fmaf(oacc[dt][r], w1r[r], o2 * w2r[r]);
            }
    }
}

extern "C" void kernel_launch(void* const* d_in, const int* in_sizes, int n_in,
                              void* d_out, int out_size, void* d_ws, size_t ws_size,
                              hipStream_t stream) {
    const float* q  = (const float*)d_in[0];
    const float* k  = (const float*)d_in[1];
    const float* v  = (const float*)d_in[2];
    const float* dm = (const float*)d_in[3];
    const float* w1 = (const float*)d_in[4];
    const float* b1 = (const float*)d_in[5];
    const float* w2 = (const float*)d_in[6];
    // d_in[7] = mix_b2: unused (softmax shift-invariant)
    float* out = (float*)d_out;
    __bf16* ws = (__bf16*)d_ws;   // needs 512*16384*2B = 16.8 MB

    prep_kernel<<<dim3(512), dim3(256), 0, stream>>>(k, v, ws);

    (void)hipFuncSetAttribute(reinterpret_cast<const void*>(msdpa_kernel),
                              hipFuncAttributeMaxDynamicSharedMemorySize, 66560);
    dim3 grid(M_ / 64, H_, B_);   // 512 blocks x 8 waves = 16 waves/CU
    msdpa_kernel<<<grid, dim3(512), 66560, stream>>>(q, ws, dm, w1, b1, w2, out);
}